// Round 7
// baseline (337.881 us; speedup 1.0000x reference)
//
#include <hip/hip_runtime.h>
#include <hip/hip_bf16.h>

#define NSEQ 2048
#define DM 512
#define BATCH 8
#define GTOT (BATCH * NSEQ)          // 16384
#define INV_T 0.044194173824159216f  // 1/sqrt(512)
#define EPSN 1e-5f

typedef __bf16 bf16_t;
typedef bf16_t bf16x8 __attribute__((ext_vector_type(8)));
typedef float f32x16 __attribute__((ext_vector_type(16)));
typedef unsigned short u16;
typedef unsigned int u32;
typedef unsigned long long u64;

__device__ __forceinline__ u16 f2bf(float f) {
    u32 u = __builtin_bit_cast(u32, f);
    u32 r = (u + 0x7FFFu + ((u >> 16) & 1u)) >> 16;
    return (u16)r;
}

// async global->LDS DMA, 16 B per lane. LDS dest = wave-uniform base + lane*16 B.
__device__ __forceinline__ void async16(const u16* g, u16* l) {
    __builtin_amdgcn_global_load_lds(
        (const __attribute__((address_space(1))) u32*)g,
        (__attribute__((address_space(3))) u32*)l, 16, 0, 0);
}

// BK=64 LDS tile: rows x 64 k-elems (128 B rows), 8 16-B chunks XOR-swizzled by ((row>>1)&7).
__device__ __forceinline__ bf16x8 fragld64(const u16* t, int row, int kc) {
    return *(const bf16x8*)(t + row * 64 + ((kc ^ ((row >> 1) & 7)) << 3));
}

#define MFMA32(a, b, c) __builtin_amdgcn_mfma_f32_32x32x16_bf16(a, b, c, 0, 0, 0)
#define ROWOFF(reg, lh) (((reg) & 3) + 8 * ((reg) >> 2) + 4 * (lh))

// BK=64 staging into explicit dest buffers: 8 issues/thread (4 A + 4 B).
// Issue u = wave*4+j covers LDS rows u*8..u*8+7; lane supplies row u*8+(lane>>3),
// chunk (lane&7), fetching the global chunk fragld64's XOR expects at that slot.
#define STAGE64D(Ag, ldA, Bg, ldB, k0, Adst, Bdst)                                   \
    do {                                                                             \
        _Pragma("unroll") for (int j = 0; j < 4; ++j) {                              \
            const int cg = (lane & 7) ^ ((j * 4 + (lane >> 4)) & 7);                 \
            const int dst = (wave * 4 + j) * 512 + lane * 8;                         \
            async16((Ag) + (long)(rS + j * 8) * (ldA) + (k0) + cg * 8, (Adst) + dst);\
            async16((Bg) + (long)(rS + j * 8) * (ldB) + (k0) + cg * 8, (Bdst) + dst);\
        }                                                                            \
    } while (0)

// --- kernel 1: mask -> bits (float4 + 4 ballots), f32 -> bf16 of X/W, zero ssbuf ---
// Mask bit layout (producer-defined, consumer matches):
//   word = row*32 + (col>>8)*4 + (col&3);  bit = (col>>2) & 63.
__global__ __launch_bounds__(256) void k_convert(
    const float* __restrict__ X, const float* __restrict__ W,
    const float* __restrict__ mask, u16* __restrict__ Kbf, u16* __restrict__ Wbf,
    u64* __restrict__ Mbits, float* __restrict__ ssbuf) {
    const int bid = blockIdx.x;
    if (bid < 32768) {
        const int w = threadIdx.x >> 6, lane = threadIdx.x & 63;
        float4 f = ((const float4*)mask)[(long)bid * 256 + threadIdx.x];
        u64 b0 = __ballot(f.x != 0.f);
        u64 b1 = __ballot(f.y != 0.f);
        u64 b2 = __ballot(f.z != 0.f);
        u64 b3 = __ballot(f.w != 0.f);
        if (lane == 0) {
            u64* p = Mbits + ((long)bid * 4 + w) * 4;
            ((ulonglong2*)p)[0] = (ulonglong2){b0, b1};
            ((ulonglong2*)p)[1] = (ulonglong2){b2, b3};
        }
        return;
    }
    const long NK = (long)GTOT * DM / 4;  // 2097152
    const long NW = (long)DM * DM / 4;    // 65536
    const long NS = GTOT / 4;             // 4096
    long i = (long)(bid - 32768) * 256 + threadIdx.x;
    if (i < NK) {
        float4 f = ((const float4*)X)[i];
        ushort4 o;
        o.x = f2bf(f.x); o.y = f2bf(f.y); o.z = f2bf(f.z); o.w = f2bf(f.w);
        ((ushort4*)Kbf)[i] = o;
    } else if (i < NK + NW) {
        long j = i - NK;
        float4 f = ((const float4*)W)[j];
        ushort4 o;
        o.x = f2bf(f.x); o.y = f2bf(f.y); o.z = f2bf(f.z); o.w = f2bf(f.w);
        ((ushort4*)Wbf)[j] = o;
    } else if (i < NK + NW + NS) {
        ((float4*)ssbuf)[i - NK - NW] = (float4){0.f, 0.f, 0.f, 0.f};
    }
}

// --- kernel 2 (FAT): blocks [0,512) = vgemm, blocks [512,2560) = sgemm ---
// Both: 128x128 tile, BK=64, 256 thr, 4 waves (2x2), wave tile 64x64 (proven).
// Independent work merged into one dispatch: saves a launch, packs vgemm's 512
// blocks into sgemm's scheduling gaps instead of a tail-heavy 2-block/CU dispatch.
__global__ __launch_bounds__(256, 4) void k_work(
    const u16* __restrict__ Kbf, const u64* __restrict__ Mbits,
    const u16* __restrict__ Wbf, const float* __restrict__ bias,
    u16* __restrict__ Sbuf, float* __restrict__ ssbuf, u16* __restrict__ vT) {
    __shared__ __attribute__((aligned(16))) u16 Ab[8192], Bb[8192];
    const int tid = threadIdx.x, wave = tid >> 6, lane = tid & 63;
    const int l31 = lane & 31, lh = lane >> 5;
    const int wy = wave >> 1, wx = wave & 1;
    const int rS = wave * 32 + (lane >> 3);
    const int bid = blockIdx.x;

    f32x16 acc[2][2];
#pragma unroll
    for (int i = 0; i < 2; ++i)
#pragma unroll
        for (int j = 0; j < 2; ++j)
#pragma unroll
            for (int e = 0; e < 16; ++e) acc[i][j][e] = 0.f;

    if (bid < 512) {
        // ---------------- vgemm: vT[e][g] = elu(W X^T + b) ----------------
        const int M0 = (bid & 3) * 128, N0 = (bid >> 2) * 128;
        const u16* Ag = Wbf + (long)M0 * DM;
        const u16* Bg = Kbf + (long)N0 * DM;

        for (int kt = 0; kt < 8; ++kt) {
            const int k0 = kt * 64;
            __syncthreads();
            STAGE64D(Ag, DM, Bg, DM, k0, Ab, Bb);
            __syncthreads();
#pragma unroll
            for (int ks = 0; ks < 4; ++ks) {
                const int kc = ks * 2 + lh;
                bf16x8 a0 = fragld64(Ab, wy * 64 + l31, kc);
                bf16x8 a1 = fragld64(Ab, wy * 64 + 32 + l31, kc);
                bf16x8 b0 = fragld64(Bb, wx * 64 + l31, kc);
                bf16x8 b1 = fragld64(Bb, wx * 64 + 32 + l31, kc);
                acc[0][0] = MFMA32(a0, b0, acc[0][0]);
                acc[0][1] = MFMA32(a0, b1, acc[0][1]);
                acc[1][0] = MFMA32(a1, b0, acc[1][0]);
                acc[1][1] = MFMA32(a1, b1, acc[1][1]);
            }
        }
#pragma unroll
        for (int mi = 0; mi < 2; ++mi) {
#pragma unroll
            for (int reg = 0; reg < 16; ++reg) {
                int e = M0 + wy * 64 + mi * 32 + ROWOFF(reg, lh);
                float bv = bias[e];
#pragma unroll
                for (int ni = 0; ni < 2; ++ni) {
                    int g = N0 + wx * 64 + ni * 32 + l31;
                    float x = acc[mi][ni][reg] + bv;
                    float v = x > 0.f ? x : (__expf(x) - 1.f);
                    vT[(long)e * GTOT + g] = f2bf(v);
                }
            }
        }
        return;
    }
    // ---- sgemm: S = bitmask .* (X X^T) * INV_T (bf16) + row sum-of-squares ----
    const int bs = bid - 512;                    // 512 % 8 == 0: XCD mapping kept
    const int b = bs & 7;                        // batch -> XCD
    const int ty = (bs >> 3) & 15, tx = bs >> 7;
    const int M0 = ty * 128, N0 = tx * 128;
    const u16* Ag = Kbf + (long)(b * NSEQ + M0) * DM;
    const u16* Bg = Kbf + (long)(b * NSEQ + N0) * DM;

    for (int kt = 0; kt < 8; ++kt) {
        const int k0 = kt * 64;
        __syncthreads();
        STAGE64D(Ag, DM, Bg, DM, k0, Ab, Bb);
        __syncthreads();
#pragma unroll
        for (int ks = 0; ks < 4; ++ks) {
            const int kc = ks * 2 + lh;
            bf16x8 a0 = fragld64(Ab, wy * 64 + l31, kc);
            bf16x8 a1 = fragld64(Ab, wy * 64 + 32 + l31, kc);
            bf16x8 b0 = fragld64(Bb, wx * 64 + l31, kc);
            bf16x8 b1 = fragld64(Bb, wx * 64 + 32 + l31, kc);
            acc[0][0] = MFMA32(a0, b0, acc[0][0]);
            acc[0][1] = MFMA32(a0, b1, acc[0][1]);
            acc[1][0] = MFMA32(a1, b0, acc[1][0]);
            acc[1][1] = MFMA32(a1, b1, acc[1][1]);
        }
    }
    // epilogue: bitmask multiply, bf16 store (L3-cached for k_pv), row sum-of-squares
#pragma unroll
    for (int mi = 0; mi < 2; ++mi) {
#pragma unroll
        for (int reg = 0; reg < 16; ++reg) {
            int rl = M0 + wy * 64 + mi * 32 + ROWOFF(reg, lh);
            long rg = (long)b * NSEQ + rl;
            const u64* Mr = Mbits + rg * 32;
            float v = 0.f;
#pragma unroll
            for (int ni = 0; ni < 2; ++ni) {
                int cg = N0 + wx * 64 + ni * 32 + l31;
                u64 wd = Mr[((cg >> 8) << 2) + (l31 & 3)];
                float s = ((wd >> ((cg >> 2) & 63)) & 1ull)
                              ? acc[mi][ni][reg] * INV_T : 0.f;
                v += s * s;
                Sbuf[rg * NSEQ + cg] = f2bf(s);
            }
            v += __shfl_xor(v, 1, 32);
            v += __shfl_xor(v, 2, 32);
            v += __shfl_xor(v, 4, 32);
            v += __shfl_xor(v, 8, 32);
            v += __shfl_xor(v, 16, 32);
            if (l31 == 0) atomicAdd(&ssbuf[rg], v);
        }
    }
}

// -------- kernel 3: O = diag(1/max(||S_row||,eps)) * (S V), 128x128 BK=64 ------
// Double-buffered, ONE barrier per K-step: stage(next) issued BEFORE compute(cur),
// __syncthreads (vmcnt+lgkm drain) after — the loads fly under the MFMA phase.
// pv is GRID-limited to 2 blocks/CU (512 blocks), so 66 KiB LDS costs zero
// occupancy — the one kernel where explicit pipelining has no downside.
__global__ __launch_bounds__(256, 2) void k_pv(
    const u16* __restrict__ Sbuf, const u16* __restrict__ vT,
    const float* __restrict__ ssbuf, float* __restrict__ Out) {
    __shared__ __attribute__((aligned(16))) u16 A0[8192], B0[8192], A1[8192], B1[8192];
    __shared__ float sc[128];
    const int tid = threadIdx.x, wave = tid >> 6, lane = tid & 63;
    const int l31 = lane & 31, lh = lane >> 5;
    const int wy = wave >> 1, wx = wave & 1;
    const int bid = blockIdx.x;
    const int b = bid & 7;                       // batch -> XCD
    const int r = bid >> 3;
    const int tx = r & 3, ty = r >> 2;
    const int M0 = ty * 128, N0 = tx * 128;
    const u16* Ag = Sbuf + (long)(b * NSEQ + M0) * NSEQ;
    const u16* Bg = vT + (long)N0 * GTOT + b * NSEQ;
    const int rS = wave * 32 + (lane >> 3);

    STAGE64D(Ag, NSEQ, Bg, GTOT, 0, A0, B0);     // prologue: tile 0 in flight
    if (tid < 128) {
        float v = ssbuf[b * NSEQ + M0 + tid];
        sc[tid] = 1.f / fmaxf(sqrtf(v), EPSN);
    }

    f32x16 acc[2][2];
#pragma unroll
    for (int i = 0; i < 2; ++i)
#pragma unroll
        for (int j = 0; j < 2; ++j)
#pragma unroll
            for (int e = 0; e < 16; ++e) acc[i][j][e] = 0.f;

    __syncthreads();                             // tile 0 landed

#define PVCOMP(Ac, Bc)                                                \
    do {                                                              \
        _Pragma("unroll") for (int ks = 0; ks < 4; ++ks) {            \
            const int kc = ks * 2 + lh;                               \
            bf16x8 a0 = fragld64((Ac), wy * 64 + l31, kc);            \
            bf16x8 a1 = fragld64((Ac), wy * 64 + 32 + l31, kc);       \
            bf16x8 b0 = fragld64((Bc), wx * 64 + l31, kc);            \
            bf16x8 b1 = fragld64((Bc), wx * 64 + 32 + l31, kc);       \
            acc[0][0] = MFMA32(a0, b0, acc[0][0]);                    \
            acc[0][1] = MFMA32(a0, b1, acc[0][1]);                    \
            acc[1][0] = MFMA32(a1, b0, acc[1][0]);                    \
            acc[1][1] = MFMA32(a1, b1, acc[1][1]);                    \
        }                                                             \
    } while (0)

    for (int t = 0; t < 16; ++t) {
        const int k0 = t * 128;
        STAGE64D(Ag, NSEQ, Bg, GTOT, k0 + 64, A1, B1);   // next half-tile in flight
        PVCOMP(A0, B0);
        __syncthreads();                                 // A1/B1 landed, A0/B0 free
        if (t < 15) STAGE64D(Ag, NSEQ, Bg, GTOT, k0 + 128, A0, B0);
        PVCOMP(A1, B1);
        __syncthreads();
    }
#undef PVCOMP

#pragma unroll
    for (int mi = 0; mi < 2; ++mi) {
#pragma unroll
        for (int reg = 0; reg < 16; ++reg) {
            int rl = wy * 64 + mi * 32 + ROWOFF(reg, lh);
            float s = sc[rl];
            float* op = Out + ((long)b * NSEQ + M0 + rl) * DM;
#pragma unroll
            for (int ni = 0; ni < 2; ++ni) {
                int d = N0 + wx * 64 + ni * 32 + l31;
                op[d] = acc[mi][ni][reg] * s;
            }
        }
    }
}

extern "C" void kernel_launch(void* const* d_in, const int* in_sizes, int n_in,
                              void* d_out, int out_size, void* d_ws, size_t ws_size,
                              hipStream_t stream) {
    const float* X = (const float*)d_in[0];
    const float* mask = (const float*)d_in[1];
    const float* W = (const float*)d_in[2];
    const float* bias = (const float*)d_in[3];
    float* out = (float*)d_out;

    char* ws = (char*)d_ws;
    u16* Kbf = (u16*)ws;                           // 16 MiB
    u16* Wbf = (u16*)(ws + 16777216);              // 512 KiB
    u16* vT = (u16*)(ws + 17301504);               // 16 MiB
    u16* Sbuf = (u16*)(ws + 34078720);             // 64 MiB
    float* ssbuf = (float*)(ws + 101187584);       // 64 KiB
    u64* Mbits = (u64*)(ws + 101253120);           // 4 MiB (packed mask)

    k_convert<<<41232, 256, 0, stream>>>(X, W, mask, Kbf, Wbf, Mbits, ssbuf);
    k_work<<<2560, 256, 0, stream>>>(Kbf, Mbits, Wbf, bias, Sbuf, ssbuf, vT);
    k_pv<<<512, 256, 0, stream>>>(Sbuf, vT, ssbuf, out);
}

// Round 8
// 335.732 us; speedup vs baseline: 1.0064x; 1.0064x over previous
//
#include <hip/hip_runtime.h>
#include <hip/hip_bf16.h>

#define NSEQ 2048
#define DM 512
#define BATCH 8
#define GTOT (BATCH * NSEQ)          // 16384
#define INV_T 0.044194173824159216f  // 1/sqrt(512)
#define EPSN 1e-5f

typedef __bf16 bf16_t;
typedef bf16_t bf16x8 __attribute__((ext_vector_type(8)));
typedef float f32x16 __attribute__((ext_vector_type(16)));
typedef unsigned short u16;
typedef unsigned int u32;
typedef unsigned long long u64;

__device__ __forceinline__ u16 f2bf(float f) {
    u32 u = __builtin_bit_cast(u32, f);
    u32 r = (u + 0x7FFFu + ((u >> 16) & 1u)) >> 16;
    return (u16)r;
}

// async global->LDS DMA, 16 B per lane. LDS dest = wave-uniform base + lane*16 B.
__device__ __forceinline__ void async16(const u16* g, u16* l) {
    __builtin_amdgcn_global_load_lds(
        (const __attribute__((address_space(1))) u32*)g,
        (__attribute__((address_space(3))) u32*)l, 16, 0, 0);
}

// BK=64 LDS tile: rows x 64 k-elems (128 B rows), 8 16-B chunks XOR-swizzled by ((row>>1)&7).
__device__ __forceinline__ bf16x8 fragld64(const u16* t, int row, int kc) {
    return *(const bf16x8*)(t + row * 64 + ((kc ^ ((row >> 1) & 7)) << 3));
}

#define MFMA32(a, b, c) __builtin_amdgcn_mfma_f32_32x32x16_bf16(a, b, c, 0, 0, 0)
#define ROWOFF(reg, lh) (((reg) & 3) + 8 * ((reg) >> 2) + 4 * (lh))

// BK=64 staging: 8 issues/thread (4 A + 4 B). Issue u = wave*4+j covers LDS rows
// u*8..u*8+7; lane supplies row u*8+(lane>>3), chunk (lane&7), fetching the
// global chunk that fragld64's XOR expects at that slot.
#define STAGE64(Ag, ldA, Bg, ldB, k0)                                            \
    do {                                                                         \
        _Pragma("unroll") for (int j = 0; j < 4; ++j) {                          \
            const int cg = (lane & 7) ^ ((j * 4 + (lane >> 4)) & 7);             \
            const int dst = (wave * 4 + j) * 512 + lane * 8;                     \
            async16((Ag) + (long)(rS + j * 8) * (ldA) + (k0) + cg * 8, Ab + dst);\
            async16((Bg) + (long)(rS + j * 8) * (ldB) + (k0) + cg * 8, Bb + dst);\
        }                                                                        \
    } while (0)

// --- kernel 1 (grid-stride, 2048 blocks): mask->bits, X/W -> bf16, zero ssbuf ---
// Mask bit layout: word = row*32 + (col>>8)*4 + (col&3);  bit = (col>>2) & 63.
// A wave's 64 float4 cover 256 consecutive cols; ballot on component j is word j.
__global__ __launch_bounds__(256) void k_convert(
    const float* __restrict__ X, const float* __restrict__ W,
    const float* __restrict__ mask, u16* __restrict__ Kbf, u16* __restrict__ Wbf,
    u64* __restrict__ Mbits, float* __restrict__ ssbuf) {
    const int gtid = blockIdx.x * 256 + threadIdx.x;   // 0..524287
    const int lane = threadIdx.x & 63;
    const float4* m4 = (const float4*)mask;
#pragma unroll
    for (int it = 0; it < 16; ++it) {                  // 8388608 float4 total
        long idx = (long)it * 524288 + gtid;
        float4 f = m4[idx];
        u64 b0 = __ballot(f.x != 0.f);
        u64 b1 = __ballot(f.y != 0.f);
        u64 b2 = __ballot(f.z != 0.f);
        u64 b3 = __ballot(f.w != 0.f);
        if (lane == 0) {
            u64* p = Mbits + ((idx >> 6) << 2);
            ((ulonglong2*)p)[0] = (ulonglong2){b0, b1};
            ((ulonglong2*)p)[1] = (ulonglong2){b2, b3};
        }
    }
#pragma unroll
    for (int it = 0; it < 4; ++it) {                   // X: 2097152 float4
        long i = (long)it * 524288 + gtid;
        float4 f = ((const float4*)X)[i];
        ushort4 o;
        o.x = f2bf(f.x); o.y = f2bf(f.y); o.z = f2bf(f.z); o.w = f2bf(f.w);
        ((ushort4*)Kbf)[i] = o;
    }
    if (gtid < 65536) {                                // W: 65536 float4
        float4 f = ((const float4*)W)[gtid];
        ushort4 o;
        o.x = f2bf(f.x); o.y = f2bf(f.y); o.z = f2bf(f.z); o.w = f2bf(f.w);
        ((ushort4*)Wbf)[gtid] = o;
    }
    if (gtid < 4096) ((float4*)ssbuf)[gtid] = (float4){0.f, 0.f, 0.f, 0.f};
}

// --- kernel 2 (FAT): blocks [0,512) = vgemm; [512,1600) = SYMMETRIC sgemm ---
// sgemm computes only upper-triangle tiles (ty<=tx, 136/batch); off-diagonal
// blocks also emit the mirrored tile (X X^T symmetric; mask applied per side).
__global__ __launch_bounds__(256, 4) void k_work(
    const u16* __restrict__ Kbf, const u64* __restrict__ Mbits,
    const u16* __restrict__ Wbf, const float* __restrict__ bias,
    u16* __restrict__ Sbuf, float* __restrict__ ssbuf, u16* __restrict__ vT) {
    __shared__ __attribute__((aligned(16))) u16 Ab[8192], Bb[8192];
    const int tid = threadIdx.x, wave = tid >> 6, lane = tid & 63;
    const int l31 = lane & 31, lh = lane >> 5;
    const int wy = wave >> 1, wx = wave & 1;
    const int rS = wave * 32 + (lane >> 3);
    const int bid = blockIdx.x;

    f32x16 acc[2][2];
#pragma unroll
    for (int i = 0; i < 2; ++i)
#pragma unroll
        for (int j = 0; j < 2; ++j)
#pragma unroll
            for (int e = 0; e < 16; ++e) acc[i][j][e] = 0.f;

    if (bid < 512) {
        // ---------------- vgemm: vT[e][g] = elu(W X^T + b) ----------------
        const int M0 = (bid & 3) * 128, N0 = (bid >> 2) * 128;
        const u16* Ag = Wbf + (long)M0 * DM;
        const u16* Bg = Kbf + (long)N0 * DM;

        for (int kt = 0; kt < 8; ++kt) {
            const int k0 = kt * 64;
            __syncthreads();
            STAGE64(Ag, DM, Bg, DM, k0);
            __syncthreads();
#pragma unroll
            for (int ks = 0; ks < 4; ++ks) {
                const int kc = ks * 2 + lh;
                bf16x8 a0 = fragld64(Ab, wy * 64 + l31, kc);
                bf16x8 a1 = fragld64(Ab, wy * 64 + 32 + l31, kc);
                bf16x8 b0 = fragld64(Bb, wx * 64 + l31, kc);
                bf16x8 b1 = fragld64(Bb, wx * 64 + 32 + l31, kc);
                acc[0][0] = MFMA32(a0, b0, acc[0][0]);
                acc[0][1] = MFMA32(a0, b1, acc[0][1]);
                acc[1][0] = MFMA32(a1, b0, acc[1][0]);
                acc[1][1] = MFMA32(a1, b1, acc[1][1]);
            }
        }
#pragma unroll
        for (int mi = 0; mi < 2; ++mi) {
#pragma unroll
            for (int reg = 0; reg < 16; ++reg) {
                int e = M0 + wy * 64 + mi * 32 + ROWOFF(reg, lh);
                float bv = bias[e];
#pragma unroll
                for (int ni = 0; ni < 2; ++ni) {
                    int g = N0 + wx * 64 + ni * 32 + l31;
                    float x = acc[mi][ni][reg] + bv;
                    float v = x > 0.f ? x : (__expf(x) - 1.f);
                    vT[(long)e * GTOT + g] = f2bf(v);
                }
            }
        }
        return;
    }
    // ---- symmetric sgemm ----
    const int bs = bid - 512;
    const int b = bs & 7;                        // batch -> XCD
    int t = bs >> 3;                             // 0..135 upper-tri tile id
    int ty = 0;
    while (t >= 16 - ty) { t -= 16 - ty; ++ty; }
    const int tx = ty + t;
    const int M0 = ty * 128, N0 = tx * 128;
    const u16* Ag = Kbf + (long)(b * NSEQ + M0) * DM;
    const u16* Bg = Kbf + (long)(b * NSEQ + N0) * DM;

    for (int kt = 0; kt < 8; ++kt) {
        const int k0 = kt * 64;
        __syncthreads();
        STAGE64(Ag, DM, Bg, DM, k0);
        __syncthreads();
#pragma unroll
        for (int ks = 0; ks < 4; ++ks) {
            const int kc = ks * 2 + lh;
            bf16x8 a0 = fragld64(Ab, wy * 64 + l31, kc);
            bf16x8 a1 = fragld64(Ab, wy * 64 + 32 + l31, kc);
            bf16x8 b0 = fragld64(Bb, wx * 64 + l31, kc);
            bf16x8 b1 = fragld64(Bb, wx * 64 + 32 + l31, kc);
            acc[0][0] = MFMA32(a0, b0, acc[0][0]);
            acc[0][1] = MFMA32(a0, b1, acc[0][1]);
            acc[1][0] = MFMA32(a1, b0, acc[1][0]);
            acc[1][1] = MFMA32(a1, b1, acc[1][1]);
        }
    }
    // ---- primary epilogue (rows ty-block, cols tx-block) ----
#pragma unroll
    for (int mi = 0; mi < 2; ++mi) {
#pragma unroll
        for (int reg = 0; reg < 16; ++reg) {
            int rl = M0 + wy * 64 + mi * 32 + ROWOFF(reg, lh);
            long rg = (long)b * NSEQ + rl;
            const u64* Mr = Mbits + rg * 32;
            float v = 0.f;
#pragma unroll
            for (int ni = 0; ni < 2; ++ni) {
                int cg = N0 + wx * 64 + ni * 32 + l31;
                u64 wd = Mr[((cg >> 8) << 2) + (l31 & 3)];
                float s = ((wd >> ((cg >> 2) & 63)) & 1ull)
                              ? acc[mi][ni][reg] * INV_T : 0.f;
                v += s * s;
                Sbuf[rg * NSEQ + cg] = f2bf(s);
            }
            v += __shfl_xor(v, 1, 32);
            v += __shfl_xor(v, 2, 32);
            v += __shfl_xor(v, 4, 32);
            v += __shfl_xor(v, 8, 32);
            v += __shfl_xor(v, 16, 32);
            if (l31 == 0) atomicAdd(&ssbuf[rg], v);
        }
    }
    // ---- mirror epilogue (rows tx-block, cols ty-block), skip on diagonal ----
    // Mirror row Rm = N0 + wx*64 + ni*32 + l31 (fixed/lane); its 64-col segment
    // [c0, c0+64) is jointly held by the lane and its lh-partner: col offset
    // q = mi*32 + (reg&3) + 8*(reg>>2) + 4*h, owner h = lh. 16-B group k =
    // (reg>>2) + 4*mi -> regs 4*k2+i, assembled via one shfl_xor(32) pair.
    if (ty != tx) {
        const int c0 = M0 + wy * 64;
        const int wb = (c0 >> 8) << 2;       // word-group base in row
        const int bb = (c0 >> 2) & 63;       // bit base (16-aligned)
#pragma unroll
        for (int ni = 0; ni < 2; ++ni) {
            const long Rg = (long)b * NSEQ + N0 + wx * 64 + ni * 32 + l31;
            const u64* Mr = Mbits + Rg * 32 + wb;
            u64 mw0 = Mr[0], mw1 = Mr[1], mw2 = Mr[2], mw3 = Mr[3];
            u16* orow = Sbuf + Rg * NSEQ + c0;
            float ssm = 0.f;
#pragma unroll
            for (int k2 = 0; k2 < 4; ++k2) {
                u16 v0[4], v1[4];
#pragma unroll
                for (int i = 0; i < 4; ++i) {
                    u64 w = (i == 0) ? mw0 : (i == 1) ? mw1 : (i == 2) ? mw2 : mw3;
                    const int bit0 = bb + 2 * k2 + lh;        // mi=0: q>>2 = 2k2+h
                    const int bit1 = bit0 + 8;                // mi=1: +8
                    float s0 = ((w >> bit0) & 1ull) ? acc[0][ni][4 * k2 + i] * INV_T : 0.f;
                    float s1 = ((w >> bit1) & 1ull) ? acc[1][ni][4 * k2 + i] * INV_T : 0.f;
                    ssm += s0 * s0 + s1 * s1;
                    v0[i] = f2bf(s0);
                    v1[i] = f2bf(s1);
                }
                u32 p0lo = v0[0] | ((u32)v0[1] << 16), p0hi = v0[2] | ((u32)v0[3] << 16);
                u32 p1lo = v1[0] | ((u32)v1[1] << 16), p1hi = v1[2] | ((u32)v1[3] << 16);
                // lane stores group k = k2 + 4*lh (cols of mi = lh); sends mi=lh^1 pack
                u32 send0 = lh ? p0lo : p1lo, send1 = lh ? p0hi : p1hi;
                u32 own0 = lh ? p1lo : p0lo, own1 = lh ? p1hi : p0hi;
                u32 r0 = (u32)__shfl_xor((int)send0, 32);
                u32 r1 = (u32)__shfl_xor((int)send1, 32);
                uint4 st;
                st.x = lh ? r0 : own0;   // cols r0..1 (h=0 half)
                st.y = lh ? r1 : own1;   // cols r2..3
                st.z = lh ? own0 : r0;   // cols r4..5 (h=1 half)
                st.w = lh ? own1 : r1;   // cols r6..7
                *(uint4*)(orow + 8 * (k2 + 4 * lh)) = st;
            }
            ssm += __shfl_xor(ssm, 32);
            if (lh == 0) atomicAdd(&ssbuf[Rg], ssm);
        }
    }
}

// -------- kernel 3: O = diag(1/max(||S_row||,eps)) * (S V), 128x128 BK=64 ------
// Round-3/6 proven structure: 256 thr, 4 waves, 1-D grid, b = bid&7 -> XCD.
__global__ __launch_bounds__(256, 4) void k_pv(
    const u16* __restrict__ Sbuf, const u16* __restrict__ vT,
    const float* __restrict__ ssbuf, float* __restrict__ Out) {
    __shared__ __attribute__((aligned(16))) u16 Ab[8192], Bb[8192];
    __shared__ float sc[128];
    const int tid = threadIdx.x, wave = tid >> 6, lane = tid & 63;
    const int l31 = lane & 31, lh = lane >> 5;
    const int wy = wave >> 1, wx = wave & 1;
    const int bid = blockIdx.x;
    const int b = bid & 7;                       // batch -> XCD
    const int r = bid >> 3;
    const int tx = r & 3, ty = r >> 2;
    const int M0 = ty * 128, N0 = tx * 128;
    const u16* Ag = Sbuf + (long)(b * NSEQ + M0) * NSEQ;
    const u16* Bg = vT + (long)N0 * GTOT + b * NSEQ;

    if (tid < 128) {
        float v = ssbuf[b * NSEQ + M0 + tid];
        sc[tid] = 1.f / fmaxf(sqrtf(v), EPSN);
    }

    const int rS = wave * 32 + (lane >> 3);

    f32x16 acc[2][2];
#pragma unroll
    for (int i = 0; i < 2; ++i)
#pragma unroll
        for (int j = 0; j < 2; ++j)
#pragma unroll
            for (int e = 0; e < 16; ++e) acc[i][j][e] = 0.f;

    for (int kt = 0; kt < 32; ++kt) {
        const int k0 = kt * 64;
        __syncthreads();
        STAGE64(Ag, NSEQ, Bg, GTOT, k0);
        __syncthreads();
#pragma unroll
        for (int ks = 0; ks < 4; ++ks) {
            const int kc = ks * 2 + lh;
            bf16x8 a0 = fragld64(Ab, wy * 64 + l31, kc);
            bf16x8 a1 = fragld64(Ab, wy * 64 + 32 + l31, kc);
            bf16x8 b0 = fragld64(Bb, wx * 64 + l31, kc);
            bf16x8 b1 = fragld64(Bb, wx * 64 + 32 + l31, kc);
            acc[0][0] = MFMA32(a0, b0, acc[0][0]);
            acc[0][1] = MFMA32(a0, b1, acc[0][1]);
            acc[1][0] = MFMA32(a1, b0, acc[1][0]);
            acc[1][1] = MFMA32(a1, b1, acc[1][1]);
        }
    }
#pragma unroll
    for (int mi = 0; mi < 2; ++mi) {
#pragma unroll
        for (int reg = 0; reg < 16; ++reg) {
            int rl = wy * 64 + mi * 32 + ROWOFF(reg, lh);
            float s = sc[rl];
            float* op = Out + ((long)b * NSEQ + M0 + rl) * DM;
#pragma unroll
            for (int ni = 0; ni < 2; ++ni) {
                int d = N0 + wx * 64 + ni * 32 + l31;
                op[d] = acc[mi][ni][reg] * s;
            }
        }
    }
}

extern "C" void kernel_launch(void* const* d_in, const int* in_sizes, int n_in,
                              void* d_out, int out_size, void* d_ws, size_t ws_size,
                              hipStream_t stream) {
    const float* X = (const float*)d_in[0];
    const float* mask = (const float*)d_in[1];
    const float* W = (const float*)d_in[2];
    const float* bias = (const float*)d_in[3];
    float* out = (float*)d_out;

    char* ws = (char*)d_ws;
    u16* Kbf = (u16*)ws;                           // 16 MiB
    u16* Wbf = (u16*)(ws + 16777216);              // 512 KiB
    u16* vT = (u16*)(ws + 17301504);               // 16 MiB
    u16* Sbuf = (u16*)(ws + 34078720);             // 64 MiB
    float* ssbuf = (float*)(ws + 101187584);       // 64 KiB
    u64* Mbits = (u64*)(ws + 101253120);           // 4 MiB (packed mask)

    k_convert<<<2048, 256, 0, stream>>>(X, W, mask, Kbf, Wbf, Mbits, ssbuf);
    k_work<<<1600, 256, 0, stream>>>(Kbf, Mbits, Wbf, bias, Sbuf, ssbuf, vT);
    k_pv<<<512, 256, 0, stream>>>(Sbuf, vT, ssbuf, out);
}

// Round 9
// 333.692 us; speedup vs baseline: 1.0126x; 1.0061x over previous
//
#include <hip/hip_runtime.h>
#include <hip/hip_bf16.h>

#define NSEQ 2048
#define DM 512
#define BATCH 8
#define GTOT (BATCH * NSEQ)          // 16384
#define INV_T 0.044194173824159216f  // 1/sqrt(512)
#define EPSN 1e-5f

typedef __bf16 bf16_t;
typedef bf16_t bf16x8 __attribute__((ext_vector_type(8)));
typedef float f32x16 __attribute__((ext_vector_type(16)));
typedef unsigned short u16;
typedef unsigned int u32;
typedef unsigned long long u64;

__device__ __forceinline__ u16 f2bf(float f) {
    u32 u = __builtin_bit_cast(u32, f);
    u32 r = (u + 0x7FFFu + ((u >> 16) & 1u)) >> 16;
    return (u16)r;
}

// async global->LDS DMA, 16 B per lane. LDS dest = wave-uniform base + lane*16 B.
__device__ __forceinline__ void async16(const u16* g, u16* l) {
    __builtin_amdgcn_global_load_lds(
        (const __attribute__((address_space(1))) u32*)g,
        (__attribute__((address_space(3))) u32*)l, 16, 0, 0);
}

// BK=64 LDS tile: rows x 64 k-elems (128 B rows), 8 16-B chunks XOR-swizzled by ((row>>1)&7).
__device__ __forceinline__ bf16x8 fragld64(const u16* t, int row, int kc) {
    return *(const bf16x8*)(t + row * 64 + ((kc ^ ((row >> 1) & 7)) << 3));
}

#define MFMA32(a, b, c) __builtin_amdgcn_mfma_f32_32x32x16_bf16(a, b, c, 0, 0, 0)
#define ROWOFF(reg, lh) (((reg) & 3) + 8 * ((reg) >> 2) + 4 * (lh))

// BK=64 staging: 8 issues/thread (4 A + 4 B). Issue u = wave*4+j covers LDS rows
// u*8..u*8+7; lane supplies row u*8+(lane>>3), chunk (lane&7), fetching the
// global chunk that fragld64's XOR expects at that slot.
#define STAGE64(Ag, ldA, Bg, ldB, k0)                                            \
    do {                                                                         \
        _Pragma("unroll") for (int j = 0; j < 4; ++j) {                          \
            const int cg = (lane & 7) ^ ((j * 4 + (lane >> 4)) & 7);             \
            const int dst = (wave * 4 + j) * 512 + lane * 8;                     \
            async16((Ag) + (long)(rS + j * 8) * (ldA) + (k0) + cg * 8, Ab + dst);\
            async16((Bg) + (long)(rS + j * 8) * (ldB) + (k0) + cg * 8, Bb + dst);\
        }                                                                        \
    } while (0)

// --- kernel 1: mask -> bits (float4 + 4 ballots), f32 -> bf16 of X/W, zero ssbuf ---
// PROVEN round-6/7 form (41232 blocks, 1 item/thread). Round-8's grid-stride
// rewrite cost +17 us (ledger) — do not re-attempt.
// Mask bit layout: word = row*32 + (col>>8)*4 + (col&3);  bit = (col>>2) & 63.
__global__ __launch_bounds__(256) void k_convert(
    const float* __restrict__ X, const float* __restrict__ W,
    const float* __restrict__ mask, u16* __restrict__ Kbf, u16* __restrict__ Wbf,
    u64* __restrict__ Mbits, float* __restrict__ ssbuf) {
    const int bid = blockIdx.x;
    if (bid < 32768) {
        const int w = threadIdx.x >> 6, lane = threadIdx.x & 63;
        float4 f = ((const float4*)mask)[(long)bid * 256 + threadIdx.x];
        u64 b0 = __ballot(f.x != 0.f);
        u64 b1 = __ballot(f.y != 0.f);
        u64 b2 = __ballot(f.z != 0.f);
        u64 b3 = __ballot(f.w != 0.f);
        if (lane == 0) {
            u64* p = Mbits + ((long)bid * 4 + w) * 4;
            ((ulonglong2*)p)[0] = (ulonglong2){b0, b1};
            ((ulonglong2*)p)[1] = (ulonglong2){b2, b3};
        }
        return;
    }
    const long NK = (long)GTOT * DM / 4;  // 2097152
    const long NW = (long)DM * DM / 4;    // 65536
    const long NS = GTOT / 4;             // 4096
    long i = (long)(bid - 32768) * 256 + threadIdx.x;
    if (i < NK) {
        float4 f = ((const float4*)X)[i];
        ushort4 o;
        o.x = f2bf(f.x); o.y = f2bf(f.y); o.z = f2bf(f.z); o.w = f2bf(f.w);
        ((ushort4*)Kbf)[i] = o;
    } else if (i < NK + NW) {
        long j = i - NK;
        float4 f = ((const float4*)W)[j];
        ushort4 o;
        o.x = f2bf(f.x); o.y = f2bf(f.y); o.z = f2bf(f.z); o.w = f2bf(f.w);
        ((ushort4*)Wbf)[j] = o;
    } else if (i < NK + NW + NS) {
        ((float4*)ssbuf)[i - NK - NW] = (float4){0.f, 0.f, 0.f, 0.f};
    }
}

// --- kernel 2 (FAT): blocks [0,512) = vgemm; [512,1600) = SYMMETRIC sgemm ---
// sgemm computes only upper-triangle tiles (ty<=tx, 136/batch); off-diagonal
// blocks also emit the mirrored tile (X X^T symmetric; mask applied per side).
__global__ __launch_bounds__(256, 4) void k_work(
    const u16* __restrict__ Kbf, const u64* __restrict__ Mbits,
    const u16* __restrict__ Wbf, const float* __restrict__ bias,
    u16* __restrict__ Sbuf, float* __restrict__ ssbuf, u16* __restrict__ vT) {
    __shared__ __attribute__((aligned(16))) u16 Ab[8192], Bb[8192];
    const int tid = threadIdx.x, wave = tid >> 6, lane = tid & 63;
    const int l31 = lane & 31, lh = lane >> 5;
    const int wy = wave >> 1, wx = wave & 1;
    const int rS = wave * 32 + (lane >> 3);
    const int bid = blockIdx.x;

    f32x16 acc[2][2];
#pragma unroll
    for (int i = 0; i < 2; ++i)
#pragma unroll
        for (int j = 0; j < 2; ++j)
#pragma unroll
            for (int e = 0; e < 16; ++e) acc[i][j][e] = 0.f;

    if (bid < 512) {
        // ---------------- vgemm: vT[e][g] = elu(W X^T + b) ----------------
        const int M0 = (bid & 3) * 128, N0 = (bid >> 2) * 128;
        const u16* Ag = Wbf + (long)M0 * DM;
        const u16* Bg = Kbf + (long)N0 * DM;

        for (int kt = 0; kt < 8; ++kt) {
            const int k0 = kt * 64;
            __syncthreads();
            STAGE64(Ag, DM, Bg, DM, k0);
            __syncthreads();
#pragma unroll
            for (int ks = 0; ks < 4; ++ks) {
                const int kc = ks * 2 + lh;
                bf16x8 a0 = fragld64(Ab, wy * 64 + l31, kc);
                bf16x8 a1 = fragld64(Ab, wy * 64 + 32 + l31, kc);
                bf16x8 b0 = fragld64(Bb, wx * 64 + l31, kc);
                bf16x8 b1 = fragld64(Bb, wx * 64 + 32 + l31, kc);
                acc[0][0] = MFMA32(a0, b0, acc[0][0]);
                acc[0][1] = MFMA32(a0, b1, acc[0][1]);
                acc[1][0] = MFMA32(a1, b0, acc[1][0]);
                acc[1][1] = MFMA32(a1, b1, acc[1][1]);
            }
        }
#pragma unroll
        for (int mi = 0; mi < 2; ++mi) {
#pragma unroll
            for (int reg = 0; reg < 16; ++reg) {
                int e = M0 + wy * 64 + mi * 32 + ROWOFF(reg, lh);
                float bv = bias[e];
#pragma unroll
                for (int ni = 0; ni < 2; ++ni) {
                    int g = N0 + wx * 64 + ni * 32 + l31;
                    float x = acc[mi][ni][reg] + bv;
                    float v = x > 0.f ? x : (__expf(x) - 1.f);
                    vT[(long)e * GTOT + g] = f2bf(v);
                }
            }
        }
        return;
    }
    // ---- symmetric sgemm ----
    const int bs = bid - 512;
    const int b = bs & 7;                        // batch -> XCD
    int t = bs >> 3;                             // 0..135 upper-tri tile id
    int ty = 0;
    while (t >= 16 - ty) { t -= 16 - ty; ++ty; }
    const int tx = ty + t;
    const int M0 = ty * 128, N0 = tx * 128;
    const u16* Ag = Kbf + (long)(b * NSEQ + M0) * DM;
    const u16* Bg = Kbf + (long)(b * NSEQ + N0) * DM;

    for (int kt = 0; kt < 8; ++kt) {
        const int k0 = kt * 64;
        __syncthreads();
        STAGE64(Ag, DM, Bg, DM, k0);
        __syncthreads();
#pragma unroll
        for (int ks = 0; ks < 4; ++ks) {
            const int kc = ks * 2 + lh;
            bf16x8 a0 = fragld64(Ab, wy * 64 + l31, kc);
            bf16x8 a1 = fragld64(Ab, wy * 64 + 32 + l31, kc);
            bf16x8 b0 = fragld64(Bb, wx * 64 + l31, kc);
            bf16x8 b1 = fragld64(Bb, wx * 64 + 32 + l31, kc);
            acc[0][0] = MFMA32(a0, b0, acc[0][0]);
            acc[0][1] = MFMA32(a0, b1, acc[0][1]);
            acc[1][0] = MFMA32(a1, b0, acc[1][0]);
            acc[1][1] = MFMA32(a1, b1, acc[1][1]);
        }
    }
    // ---- primary epilogue (rows ty-block, cols tx-block) ----
#pragma unroll
    for (int mi = 0; mi < 2; ++mi) {
#pragma unroll
        for (int reg = 0; reg < 16; ++reg) {
            int rl = M0 + wy * 64 + mi * 32 + ROWOFF(reg, lh);
            long rg = (long)b * NSEQ + rl;
            const u64* Mr = Mbits + rg * 32;
            float v = 0.f;
#pragma unroll
            for (int ni = 0; ni < 2; ++ni) {
                int cg = N0 + wx * 64 + ni * 32 + l31;
                u64 wd = Mr[((cg >> 8) << 2) + (l31 & 3)];
                float s = ((wd >> ((cg >> 2) & 63)) & 1ull)
                              ? acc[mi][ni][reg] * INV_T : 0.f;
                v += s * s;
                Sbuf[rg * NSEQ + cg] = f2bf(s);
            }
            v += __shfl_xor(v, 1, 32);
            v += __shfl_xor(v, 2, 32);
            v += __shfl_xor(v, 4, 32);
            v += __shfl_xor(v, 8, 32);
            v += __shfl_xor(v, 16, 32);
            if (l31 == 0) atomicAdd(&ssbuf[rg], v);
        }
    }
    // ---- mirror epilogue (rows tx-block, cols ty-block), skip on diagonal ----
    if (ty != tx) {
        const int c0 = M0 + wy * 64;
        const int wb = (c0 >> 8) << 2;       // word-group base in row
        const int bb = (c0 >> 2) & 63;       // bit base (16-aligned)
#pragma unroll
        for (int ni = 0; ni < 2; ++ni) {
            const long Rg = (long)b * NSEQ + N0 + wx * 64 + ni * 32 + l31;
            const u64* Mr = Mbits + Rg * 32 + wb;
            u64 mw0 = Mr[0], mw1 = Mr[1], mw2 = Mr[2], mw3 = Mr[3];
            u16* orow = Sbuf + Rg * NSEQ + c0;
            float ssm = 0.f;
#pragma unroll
            for (int k2 = 0; k2 < 4; ++k2) {
                u16 v0[4], v1[4];
#pragma unroll
                for (int i = 0; i < 4; ++i) {
                    u64 w = (i == 0) ? mw0 : (i == 1) ? mw1 : (i == 2) ? mw2 : mw3;
                    const int bit0 = bb + 2 * k2 + lh;        // mi=0: q>>2 = 2k2+h
                    const int bit1 = bit0 + 8;                // mi=1: +8
                    float s0 = ((w >> bit0) & 1ull) ? acc[0][ni][4 * k2 + i] * INV_T : 0.f;
                    float s1 = ((w >> bit1) & 1ull) ? acc[1][ni][4 * k2 + i] * INV_T : 0.f;
                    ssm += s0 * s0 + s1 * s1;
                    v0[i] = f2bf(s0);
                    v1[i] = f2bf(s1);
                }
                u32 p0lo = v0[0] | ((u32)v0[1] << 16), p0hi = v0[2] | ((u32)v0[3] << 16);
                u32 p1lo = v1[0] | ((u32)v1[1] << 16), p1hi = v1[2] | ((u32)v1[3] << 16);
                u32 send0 = lh ? p0lo : p1lo, send1 = lh ? p0hi : p1hi;
                u32 own0 = lh ? p1lo : p0lo, own1 = lh ? p1hi : p0hi;
                u32 r0 = (u32)__shfl_xor((int)send0, 32);
                u32 r1 = (u32)__shfl_xor((int)send1, 32);
                uint4 st;
                st.x = lh ? r0 : own0;
                st.y = lh ? r1 : own1;
                st.z = lh ? own0 : r0;
                st.w = lh ? own1 : r1;
                *(uint4*)(orow + 8 * (k2 + 4 * lh)) = st;
            }
            ssm += __shfl_xor(ssm, 32);
            if (lh == 0) atomicAdd(&ssbuf[Rg], ssm);
        }
    }
}

// -------- kernel 3: O = diag(1/max(||S_row||,eps)) * (S V), 128x128 BK=64 ------
// Proven structure: 256 thr, 4 waves, 1-D grid, b = bid&7 -> XCD.
__global__ __launch_bounds__(256, 4) void k_pv(
    const u16* __restrict__ Sbuf, const u16* __restrict__ vT,
    const float* __restrict__ ssbuf, float* __restrict__ Out) {
    __shared__ __attribute__((aligned(16))) u16 Ab[8192], Bb[8192];
    __shared__ float sc[128];
    const int tid = threadIdx.x, wave = tid >> 6, lane = tid & 63;
    const int l31 = lane & 31, lh = lane >> 5;
    const int wy = wave >> 1, wx = wave & 1;
    const int bid = blockIdx.x;
    const int b = bid & 7;                       // batch -> XCD
    const int r = bid >> 3;
    const int tx = r & 3, ty = r >> 2;
    const int M0 = ty * 128, N0 = tx * 128;
    const u16* Ag = Sbuf + (long)(b * NSEQ + M0) * NSEQ;
    const u16* Bg = vT + (long)N0 * GTOT + b * NSEQ;

    if (tid < 128) {
        float v = ssbuf[b * NSEQ + M0 + tid];
        sc[tid] = 1.f / fmaxf(sqrtf(v), EPSN);
    }

    const int rS = wave * 32 + (lane >> 3);

    f32x16 acc[2][2];
#pragma unroll
    for (int i = 0; i < 2; ++i)
#pragma unroll
        for (int j = 0; j < 2; ++j)
#pragma unroll
            for (int e = 0; e < 16; ++e) acc[i][j][e] = 0.f;

    for (int kt = 0; kt < 32; ++kt) {
        const int k0 = kt * 64;
        __syncthreads();
        STAGE64(Ag, NSEQ, Bg, GTOT, k0);
        __syncthreads();
#pragma unroll
        for (int ks = 0; ks < 4; ++ks) {
            const int kc = ks * 2 + lh;
            bf16x8 a0 = fragld64(Ab, wy * 64 + l31, kc);
            bf16x8 a1 = fragld64(Ab, wy * 64 + 32 + l31, kc);
            bf16x8 b0 = fragld64(Bb, wx * 64 + l31, kc);
            bf16x8 b1 = fragld64(Bb, wx * 64 + 32 + l31, kc);
            acc[0][0] = MFMA32(a0, b0, acc[0][0]);
            acc[0][1] = MFMA32(a0, b1, acc[0][1]);
            acc[1][0] = MFMA32(a1, b0, acc[1][0]);
            acc[1][1] = MFMA32(a1, b1, acc[1][1]);
        }
    }
#pragma unroll
    for (int mi = 0; mi < 2; ++mi) {
#pragma unroll
        for (int reg = 0; reg < 16; ++reg) {
            int rl = wy * 64 + mi * 32 + ROWOFF(reg, lh);
            float s = sc[rl];
            float* op = Out + ((long)b * NSEQ + M0 + rl) * DM;
#pragma unroll
            for (int ni = 0; ni < 2; ++ni) {
                int d = N0 + wx * 64 + ni * 32 + l31;
                op[d] = acc[mi][ni][reg] * s;
            }
        }
    }
}

extern "C" void kernel_launch(void* const* d_in, const int* in_sizes, int n_in,
                              void* d_out, int out_size, void* d_ws, size_t ws_size,
                              hipStream_t stream) {
    const float* X = (const float*)d_in[0];
    const float* mask = (const float*)d_in[1];
    const float* W = (const float*)d_in[2];
    const float* bias = (const float*)d_in[3];
    float* out = (float*)d_out;

    char* ws = (char*)d_ws;
    u16* Kbf = (u16*)ws;                           // 16 MiB
    u16* Wbf = (u16*)(ws + 16777216);              // 512 KiB
    u16* vT = (u16*)(ws + 17301504);               // 16 MiB
    u16* Sbuf = (u16*)(ws + 34078720);             // 64 MiB
    float* ssbuf = (float*)(ws + 101187584);       // 64 KiB
    u64* Mbits = (u64*)(ws + 101253120);           // 4 MiB (packed mask)

    k_convert<<<41232, 256, 0, stream>>>(X, W, mask, Kbf, Wbf, Mbits, ssbuf);
    k_work<<<1600, 256, 0, stream>>>(Kbf, Mbits, Wbf, bias, Sbuf, ssbuf, vT);
    k_pv<<<512, 256, 0, stream>>>(Sbuf, vT, ssbuf, out);
}